// Round 1
// baseline (1327.722 us; speedup 1.0000x reference)
//
#include <hip/hip_runtime.h>

#define T_STEPS 256
#define BATCH   2048
#define INSZ    65
#define HID     64
#define ROWS    2        // batch rows per block -> 1024 blocks = 4 blocks/CU (was 2)
#define OUTSZ   7
#define NTHREADS 256

// LDS slot bases (shorts). Frag-major layout inside each 256-short slot:
// element (row, k) at (k>>3)*32 + row*8 + (k&7).  b128 frag reads: <=2-way/bank.
#define XS0 0
#define XS1 256
#define HS0 512
#define HS1 768

typedef __attribute__((ext_vector_type(8))) short bf16x8;  // 8 bf16 = 4 VGPRs
typedef __attribute__((ext_vector_type(4))) float f32x4;

// hardware RNE f32->bf16 (1 instr vs 5-op manual rounder; on h critical path)
__device__ __forceinline__ short f2bf(float f) {
    unsigned o;
    asm("v_cvt_pk_bf16_f32 %0, %1, %2" : "=v"(o) : "v"(f), "v"(0.0f));
    return (short)o;
}
__device__ __forceinline__ float bf2f(short s) {
    union { unsigned u; float f; } v;
    v.u = ((unsigned)(unsigned short)s) << 16;
    return v.f;
}

// Gate pre-activations arrive PRE-SCALED (folded into weights/bias):
//   i,f,o scaled by -log2(e)  -> sigmoid(x) = rcp(1 + exp2(x'))
//   g     scaled by +2log2(e) -> tanh(x)    = 1 - 2*rcp(1 + exp2(x'))
// Raw v_exp_f32 / v_rcp_f32 (no Newton refine): ~3-4 op chain per activation.
#define NLOG2E -1.4426950408889634f
#define SGSCL   2.8853900817779268f

__device__ __forceinline__ float sigm2(float a) {
    return __builtin_amdgcn_rcpf(1.0f + __builtin_amdgcn_exp2f(a));
}
__device__ __forceinline__ float tanh2(float a) {   // a already scaled by 2log2e
    return 1.0f - 2.0f * __builtin_amdgcn_rcpf(1.0f + __builtin_amdgcn_exp2f(a));
}

__global__ __launch_bounds__(NTHREADS, 4)
void lstm_fused(const float* __restrict__ x,    const float* __restrict__ W_ih,
                const float* __restrict__ W_hh, const float* __restrict__ b_ih,
                const float* __restrict__ b_hh, const float* __restrict__ fc_W,
                const float* __restrict__ fc_b, float* __restrict__ out)
{
    __shared__ __align__(16) short Abuf[1024];

    const int tid  = threadIdx.x;
    const int w    = tid >> 6;        // wave 0..3 = hidden-col tile [16w,16w+16)
    const int lane = tid & 63;
    const int quad = lane >> 4;
    const int col  = lane & 15;
    const int b0   = blockIdx.x * ROWS;

    // zero h slots only (x slots are fully staged before first read)
    Abuf[HS0 + tid] = 0;
    Abuf[HS1 + tid] = 0;

    // ---- weight fragments (B layout: n = lane&15, k = quad*8+j), pre-scaled ----
    // kc 0,1: x-part (k 0..63 of W_ih); kc 2,3: h-part (W_hh). k=64 -> acc_x fold.
    bf16x8 wfrag[4][4];
    float  wl[4];
    f32x4  bias4[4];
    #pragma unroll
    for (int gt = 0; gt < 4; ++gt) {
        const float sc = (gt == 2) ? SGSCL : NLOG2E;
        const int n = gt * 64 + w * 16 + col;
        #pragma unroll
        for (int kc = 0; kc < 2; ++kc) {
            bf16x8 f;
            #pragma unroll
            for (int j = 0; j < 8; ++j)
                f[j] = f2bf(W_ih[n * INSZ + kc * 32 + quad * 8 + j] * sc);
            wfrag[gt][kc] = f;
        }
        #pragma unroll
        for (int kc = 2; kc < 4; ++kc) {
            bf16x8 f;
            #pragma unroll
            for (int j = 0; j < 8; ++j)
                f[j] = f2bf(W_hh[n * HID + (kc - 2) * 32 + quad * 8 + j] * sc);
            wfrag[gt][kc] = f;
        }
        wl[gt] = W_ih[n * INSZ + 64] * sc;
        const float bv = (b_ih[n] + b_hh[n]) * sc;
        bias4[gt] = (f32x4){bv, bv, bv, bv};
    }

    // A-frag replication: M-row m supplies data row m>>2 (was m&3). Then lane
    // (quad q, col c) holds C rows 4q..4q+3 which ALL map to data row q ->
    // gate value = acc[gt][0], no sel4 cndmasks, no lane-select on the chain.
    const int rbase = quad * 32 + (col >> 2) * 8;              // frag read
    const int hwoff = (2 * w + (col >> 3)) * 32 + quad * 8 + (col & 7);  // h write
    const int xwoff = (lane >> 3) * 32 + w * 8 + (lane & 7);   // x stage write

    // ROWS=2: waves 2,3 / quads 2,3 duplicate rows 0,1 (exact duplicates, no OOB)
    const float* xsp = x + (size_t)(b0 + (w & 1))    * T_STEPS * INSZ + lane;
    const float* xep = x + (size_t)(b0 + (quad & 1)) * T_STEPS * INSZ + 64;

    // stage x_0 -> XS0, x_1 -> XS1; init 4-step register pipelines
    Abuf[XS0 + xwoff] = f2bf(xsp[0]);
    Abuf[XS1 + xwoff] = f2bf(xsp[INSZ]);
    float stg[4], fix[4];                 // stg: x_{t+2..t+5}; fix: x_{t+1..t+4}[64]
    const float fix0 = xep[0];
    #pragma unroll
    for (int i = 0; i < 4; ++i) {
        stg[i] = xsp[(2 + i) * INSZ];
        fix[i] = xep[(1 + i) * INSZ];
    }
    float c = 0.0f;
    f32x4 acc_x[4];
    __syncthreads();

    // acc_x(x_0) = bias + x_0 . W_ih, with the k=64 fixup folded in off-path
    {
        const bf16x8 n0 = *(const bf16x8*)&Abuf[XS0 + rbase];
        const bf16x8 n1 = *(const bf16x8*)&Abuf[XS0 + rbase + 128];
        #pragma unroll
        for (int gt = 0; gt < 4; ++gt) {
            f32x4 a = __builtin_amdgcn_mfma_f32_16x16x32_bf16(n0, wfrag[gt][0], bias4[gt], 0, 0, 0);
            acc_x[gt] = __builtin_amdgcn_mfma_f32_16x16x32_bf16(n1, wfrag[gt][1], a, 0, 0, 0);
            acc_x[gt][0] = __builtin_fmaf(wl[gt], fix0, acc_x[gt][0]);
        }
    }
    __syncthreads();    // x_0 frag reads done before body 0 overwrites XS0

    // one LSTM step. Critical path: ds_read h -> 8 MFMA -> activation -> h write.
    // acc_x for t+1 (8 MFMA + fixup fold) runs in the shadow of the activation.
    auto STEP = [&](int XR, int XW, int HR, int HW, float xfixn, float xstage) {
        const bf16x8 a2 = *(const bf16x8*)&Abuf[HR + rbase];        // h lo
        const bf16x8 a3 = *(const bf16x8*)&Abuf[HR + rbase + 128];  // h hi
        const bf16x8 n0 = *(const bf16x8*)&Abuf[XR + rbase];        // x_{t+1} lo
        const bf16x8 n1 = *(const bf16x8*)&Abuf[XR + rbase + 128];  // x_{t+1} hi
        f32x4 acc[4];
        #pragma unroll
        for (int gt = 0; gt < 4; ++gt) {
            f32x4 a = __builtin_amdgcn_mfma_f32_16x16x32_bf16(a2, wfrag[gt][2], acc_x[gt], 0, 0, 0);
            acc[gt]  = __builtin_amdgcn_mfma_f32_16x16x32_bf16(a3, wfrag[gt][3], a, 0, 0, 0);
        }
        const float gi = sigm2(acc[0][0]);
        const float gf = sigm2(acc[1][0]);
        const float gg = tanh2(acc[2][0]);
        const float go = sigm2(acc[3][0]);
        c = gf * c + gi * gg;
        const float h = go * tanh2(SGSCL * c);
        Abuf[HW + hwoff] = f2bf(h);          // h_t
        Abuf[XW + xwoff] = f2bf(xstage);     // x_{t+2}
        #pragma unroll
        for (int gt = 0; gt < 4; ++gt) {     // acc_x for step t+1 (off critical path)
            f32x4 a = __builtin_amdgcn_mfma_f32_16x16x32_bf16(n0, wfrag[gt][0], bias4[gt], 0, 0, 0);
            acc_x[gt] = __builtin_amdgcn_mfma_f32_16x16x32_bf16(n1, wfrag[gt][1], a, 0, 0, 0);
            acc_x[gt][0] = __builtin_fmaf(wl[gt], xfixn, acc_x[gt][0]);
        }
        __syncthreads();
    };

    for (int t = 0; t < T_STEPS; t += 4) {
        // all global loads for the NEXT 4-step group, issued right after a barrier
        float ns[4], nf[4];
        #pragma unroll
        for (int i = 0; i < 4; ++i) {
            const int ts = t + 6 + i;  // stage x_{t+6+i} (clamped tail: unused)
            const int tf = t + 5 + i;  // fixup x_{t+5+i}[64]
            ns[i] = xsp[(ts < 255 ? ts : 255) * INSZ];
            nf[i] = xep[(tf < 255 ? tf : 255) * INSZ];
        }
        STEP(XS1, XS0, HS1, HS0, fix[0], stg[0]);   // t   : h in HS1, x_{t+1} in XS1
        STEP(XS0, XS1, HS0, HS1, fix[1], stg[1]);   // t+1
        STEP(XS1, XS0, HS1, HS0, fix[2], stg[2]);   // t+2
        STEP(XS0, XS1, HS0, HS1, fix[3], stg[3]);   // t+3
        #pragma unroll
        for (int i = 0; i < 4; ++i) { stg[i] = ns[i]; fix[i] = nf[i]; }
    }

    // ---- FC(64->7) + sigmoid; h_255 lives in HS1 (frag-major) ----
    if (tid < ROWS * OUTSZ) {
        const int m = tid % ROWS;
        const int o = tid / ROWS;
        float s = fc_b[o];
        #pragma unroll
        for (int k = 0; k < HID; ++k)
            s += bf2f(Abuf[HS1 + (k >> 3) * 32 + m * 8 + (k & 7)]) * fc_W[o * HID + k];
        out[(size_t)(b0 + m) * OUTSZ + o] =
            __builtin_amdgcn_rcpf(1.0f + __builtin_amdgcn_exp2f(NLOG2E * s));
    }
}

extern "C" void kernel_launch(void* const* d_in, const int* in_sizes, int n_in,
                              void* d_out, int out_size, void* d_ws, size_t ws_size,
                              hipStream_t stream) {
    const float* x    = (const float*)d_in[0];
    const float* W_ih = (const float*)d_in[1];
    const float* W_hh = (const float*)d_in[2];
    const float* b_ih = (const float*)d_in[3];
    const float* b_hh = (const float*)d_in[4];
    const float* fc_W = (const float*)d_in[5];
    const float* fc_b = (const float*)d_in[6];
    float* out = (float*)d_out;

    dim3 grid(BATCH / ROWS);    // 1024 blocks -> 4 per CU
    dim3 block(NTHREADS);       // 4 waves
    hipLaunchKernelGGL(lstm_fused, grid, block, 0, stream,
                       x, W_ih, W_hh, b_ih, b_hh, fc_W, fc_b, out);
}

// Round 3
// 361.062 us; speedup vs baseline: 3.6773x; 3.6773x over previous
//
#include <hip/hip_runtime.h>
#include <hip/hip_bf16.h>

#define T_STEPS 256
#define BATCH   2048
#define INSZ    65
#define HID     64
#define ROWS    2        // batch rows per block -> 1024 blocks = 4 blocks/CU
#define OUTSZ   7
#define NTHREADS 256

// LDS slot bases (shorts). Frag-major layout inside each 256-short slot:
// element (row, k) at (k>>3)*32 + row*8 + (k&7).  b128 frag reads: <=2-way/bank.
#define XS0 0
#define XS1 256
#define HS0 512
#define HS1 768

typedef __attribute__((ext_vector_type(8))) short bf16x8;  // 8 bf16 = 4 VGPRs
typedef __attribute__((ext_vector_type(4))) float f32x4;

// f32->bf16 RNE via HIP intrinsic — NO inline asm. Round-2 post-mortem: the
// non-volatile asm v_cvt_pk_bf16_f32 was the only schedule-sensitive delta in
// the config that NaN'd; __float2bfloat16 is compiler-visible and safe.
__device__ __forceinline__ short f2bf(float f) {
    __hip_bfloat16 b = __float2bfloat16(f);
    return (short)__builtin_bit_cast(unsigned short, b);
}
__device__ __forceinline__ float bf2f(short s) {
    union { unsigned u; float f; } v;
    v.u = ((unsigned)(unsigned short)s) << 16;
    return v.f;
}

// Gate pre-activations arrive PRE-SCALED (folded into weights/bias):
//   i,f,o scaled by -log2(e)  -> sigmoid(x) = rcp(1 + exp2(x'))
//   g     scaled by +2log2(e) -> tanh(x)    = 1 - 2*rcp(1 + exp2(x'))
// Raw v_exp_f32 / v_rcp_f32 (no Newton refine): ~3-op chain per activation.
#define NLOG2E -1.4426950408889634f
#define SGSCL   2.8853900817779268f

__device__ __forceinline__ float sigm2(float a) {
    return __builtin_amdgcn_rcpf(1.0f + __builtin_amdgcn_exp2f(a));
}
__device__ __forceinline__ float tanh2(float a) {   // a already scaled by 2log2e
    return 1.0f - 2.0f * __builtin_amdgcn_rcpf(1.0f + __builtin_amdgcn_exp2f(a));
}

// launch_bounds(.,2): VGPR cap 256 -> ~100 alloc, no spill (round-0 proven).
// (.,4) capped arch VGPRs at 64 -> 909 MB scratch traffic (round-1 post-mortem).
// Residency: VGPR~100 -> 4 waves/SIMD -> 4 blocks/CU with grid=1024.
__global__ __launch_bounds__(NTHREADS, 2)
void lstm_fused(const float* __restrict__ x,    const float* __restrict__ W_ih,
                const float* __restrict__ W_hh, const float* __restrict__ b_ih,
                const float* __restrict__ b_hh, const float* __restrict__ fc_W,
                const float* __restrict__ fc_b, float* __restrict__ out)
{
    __shared__ __align__(16) short Abuf[1024];

    const int tid  = threadIdx.x;
    const int w    = tid >> 6;        // wave 0..3 = hidden-col tile [16w,16w+16)
    const int lane = tid & 63;
    const int quad = lane >> 4;
    const int col  = lane & 15;
    const int b0   = blockIdx.x * ROWS;

    // zero h slots only (x slots are fully staged before first read)
    Abuf[HS0 + tid] = 0;
    Abuf[HS1 + tid] = 0;

    // ---- weight fragments (B layout: n = lane&15, k = quad*8+j), pre-scaled ----
    // kc 0,1: x-part (k 0..63 of W_ih); kc 2,3: h-part (W_hh). k=64 -> acc_x fold.
    bf16x8 wfrag[4][4];
    float  wl[4];
    f32x4  bias4[4];
    #pragma unroll
    for (int gt = 0; gt < 4; ++gt) {
        const float sc = (gt == 2) ? SGSCL : NLOG2E;
        const int n = gt * 64 + w * 16 + col;
        #pragma unroll
        for (int kc = 0; kc < 2; ++kc) {
            bf16x8 f;
            #pragma unroll
            for (int j = 0; j < 8; ++j)
                f[j] = f2bf(W_ih[n * INSZ + kc * 32 + quad * 8 + j] * sc);
            wfrag[gt][kc] = f;
        }
        #pragma unroll
        for (int kc = 2; kc < 4; ++kc) {
            bf16x8 f;
            #pragma unroll
            for (int j = 0; j < 8; ++j)
                f[j] = f2bf(W_hh[n * HID + (kc - 2) * 32 + quad * 8 + j] * sc);
            wfrag[gt][kc] = f;
        }
        wl[gt] = W_ih[n * INSZ + 64] * sc;
        const float bv = (b_ih[n] + b_hh[n]) * sc;
        bias4[gt] = (f32x4){bv, bv, bv, bv};
    }

    // A-frag replication: M-row m supplies data row m>>2. Then lane (quad q)
    // holds C rows 4q..4q+3 which ALL map to data row q -> gate = acc[gt][0],
    // no sel4 cndmasks on the serial chain. (Verified correct in round 1.)
    const int rbase = quad * 32 + (col >> 2) * 8;              // frag read
    const int hwoff = (2 * w + (col >> 3)) * 32 + quad * 8 + (col & 7);  // h write
    const int xwoff = (lane >> 3) * 32 + w * 8 + (lane & 7);   // x stage write

    // ROWS=2: waves 2,3 / quads 2,3 duplicate rows 0,1 (exact duplicates, no OOB)
    const float* xsp = x + (size_t)(b0 + (w & 1))    * T_STEPS * INSZ + lane;
    const float* xep = x + (size_t)(b0 + (quad & 1)) * T_STEPS * INSZ + 64;

    // stage x_0 -> XS0, x_1 -> XS1; init 4-step register pipelines
    Abuf[XS0 + xwoff] = f2bf(xsp[0]);
    Abuf[XS1 + xwoff] = f2bf(xsp[INSZ]);
    float stg[4], fix[4];                 // stg: x_{t+2..t+5}; fix: x_{t+1..t+4}[64]
    const float fix0 = xep[0];
    #pragma unroll
    for (int i = 0; i < 4; ++i) {
        stg[i] = xsp[(2 + i) * INSZ];
        fix[i] = xep[(1 + i) * INSZ];
    }
    float c = 0.0f;
    f32x4 acc_x[4];
    __syncthreads();

    // acc_x(x_0) = bias + x_0 . W_ih, with the k=64 fixup folded in off-path
    {
        const bf16x8 n0 = *(const bf16x8*)&Abuf[XS0 + rbase];
        const bf16x8 n1 = *(const bf16x8*)&Abuf[XS0 + rbase + 128];
        #pragma unroll
        for (int gt = 0; gt < 4; ++gt) {
            f32x4 a = __builtin_amdgcn_mfma_f32_16x16x32_bf16(n0, wfrag[gt][0], bias4[gt], 0, 0, 0);
            acc_x[gt] = __builtin_amdgcn_mfma_f32_16x16x32_bf16(n1, wfrag[gt][1], a, 0, 0, 0);
            acc_x[gt][0] = __builtin_fmaf(wl[gt], fix0, acc_x[gt][0]);
        }
    }
    __syncthreads();    // x_0 frag reads done before body 0 overwrites XS0

    // one LSTM step. Critical path: ds_read h -> 8 MFMA -> activation -> h write.
    // acc_x for t+1 (8 MFMA + fixup fold) runs in the shadow of the activation.
    auto STEP = [&](int XR, int XW, int HR, int HW, float xfixn, float xstage) {
        const bf16x8 a2 = *(const bf16x8*)&Abuf[HR + rbase];        // h lo
        const bf16x8 a3 = *(const bf16x8*)&Abuf[HR + rbase + 128];  // h hi
        const bf16x8 n0 = *(const bf16x8*)&Abuf[XR + rbase];        // x_{t+1} lo
        const bf16x8 n1 = *(const bf16x8*)&Abuf[XR + rbase + 128];  // x_{t+1} hi
        f32x4 acc[4];
        #pragma unroll
        for (int gt = 0; gt < 4; ++gt) {
            f32x4 a = __builtin_amdgcn_mfma_f32_16x16x32_bf16(a2, wfrag[gt][2], acc_x[gt], 0, 0, 0);
            acc[gt]  = __builtin_amdgcn_mfma_f32_16x16x32_bf16(a3, wfrag[gt][3], a, 0, 0, 0);
        }
        const float gi = sigm2(acc[0][0]);
        const float gf = sigm2(acc[1][0]);
        const float gg = tanh2(acc[2][0]);
        const float go = sigm2(acc[3][0]);
        c = gf * c + gi * gg;
        const float h = go * tanh2(SGSCL * c);
        Abuf[HW + hwoff] = f2bf(h);          // h_t
        Abuf[XW + xwoff] = f2bf(xstage);     // x_{t+2}
        #pragma unroll
        for (int gt = 0; gt < 4; ++gt) {     // acc_x for step t+1 (off critical path)
            f32x4 a = __builtin_amdgcn_mfma_f32_16x16x32_bf16(n0, wfrag[gt][0], bias4[gt], 0, 0, 0);
            acc_x[gt] = __builtin_amdgcn_mfma_f32_16x16x32_bf16(n1, wfrag[gt][1], a, 0, 0, 0);
            acc_x[gt][0] = __builtin_fmaf(wl[gt], xfixn, acc_x[gt][0]);
        }
        __syncthreads();
    };

    for (int t = 0; t < T_STEPS; t += 4) {
        // all global loads for the NEXT 4-step group, issued right after a barrier
        float ns[4], nf[4];
        #pragma unroll
        for (int i = 0; i < 4; ++i) {
            const int ts = t + 6 + i;  // stage x_{t+6+i} (clamped tail: unused)
            const int tf = t + 5 + i;  // fixup x_{t+5+i}[64]
            ns[i] = xsp[(ts < 255 ? ts : 255) * INSZ];
            nf[i] = xep[(tf < 255 ? tf : 255) * INSZ];
        }
        STEP(XS1, XS0, HS1, HS0, fix[0], stg[0]);   // t   : h in HS1, x_{t+1} in XS1
        STEP(XS0, XS1, HS0, HS1, fix[1], stg[1]);   // t+1
        STEP(XS1, XS0, HS1, HS0, fix[2], stg[2]);   // t+2
        STEP(XS0, XS1, HS0, HS1, fix[3], stg[3]);   // t+3
        #pragma unroll
        for (int i = 0; i < 4; ++i) { stg[i] = ns[i]; fix[i] = nf[i]; }
    }

    // ---- FC(64->7) + sigmoid; h_255 lives in HS1 (frag-major) ----
    if (tid < ROWS * OUTSZ) {
        const int m = tid % ROWS;
        const int o = tid / ROWS;
        float s = fc_b[o];
        #pragma unroll
        for (int k = 0; k < HID; ++k)
            s += bf2f(Abuf[HS1 + (k >> 3) * 32 + m * 8 + (k & 7)]) * fc_W[o * HID + k];
        out[(size_t)(b0 + m) * OUTSZ + o] =
            __builtin_amdgcn_rcpf(1.0f + __builtin_amdgcn_exp2f(NLOG2E * s));
    }
}

extern "C" void kernel_launch(void* const* d_in, const int* in_sizes, int n_in,
                              void* d_out, int out_size, void* d_ws, size_t ws_size,
                              hipStream_t stream) {
    const float* x    = (const float*)d_in[0];
    const float* W_ih = (const float*)d_in[1];
    const float* W_hh = (const float*)d_in[2];
    const float* b_ih = (const float*)d_in[3];
    const float* b_hh = (const float*)d_in[4];
    const float* fc_W = (const float*)d_in[5];
    const float* fc_b = (const float*)d_in[6];
    float* out = (float*)d_out;

    dim3 grid(BATCH / ROWS);    // 1024 blocks -> 4 per CU
    dim3 block(NTHREADS);       // 4 waves
    hipLaunchKernelGGL(lstm_fused, grid, block, 0, stream,
                       x, W_ih, W_hh, b_ih, b_hh, fc_W, fc_b, out);
}

// Round 4
// 265.995 us; speedup vs baseline: 4.9915x; 1.3574x over previous
//
#include <hip/hip_runtime.h>
#include <hip/hip_bf16.h>

#define T_STEPS 256
#define BATCH   2048
#define INSZ    65
#define HID     64
#define ROWS    4        // batch rows per block -> 512 blocks = 2 blocks/CU
#define OUTSZ   7
#define NTHREADS 256

// LDS slot bases (shorts). Frag-major layout inside each 256-short slot:
// element (row, k) at (k>>3)*32 + row*8 + (k&7).  b128 frag reads: <=2-way/bank.
#define XS0 0
#define XS1 256
#define HS0 512
#define HS1 768

typedef __attribute__((ext_vector_type(8))) short bf16x8;  // 8 bf16 = 4 VGPRs
typedef __attribute__((ext_vector_type(4))) float f32x4;

// f32->bf16 RNE via HIP intrinsic (round-2 post-mortem: no inline-asm cvt).
__device__ __forceinline__ short f2bf(float f) {
    __hip_bfloat16 b = __float2bfloat16(f);
    return (short)__builtin_bit_cast(unsigned short, b);
}
__device__ __forceinline__ float bf2f(short s) {
    union { unsigned u; float f; } v;
    v.u = ((unsigned)(unsigned short)s) << 16;
    return v.f;
}

// Gate pre-activations arrive PRE-SCALED (folded into weights/bias):
//   i,f,o scaled by -log2(e)  -> sigmoid(x) = rcp(1 + exp2(x'))
//   g     scaled by +2log2(e) -> tanh(x)    = 1 - 2*rcp(1 + exp2(x'))
#define NLOG2E -1.4426950408889634f
#define SGSCL   2.8853900817779268f

__device__ __forceinline__ float sigm2(float a) {
    return __builtin_amdgcn_rcpf(1.0f + __builtin_amdgcn_exp2f(a));
}
__device__ __forceinline__ float tanh2(float a) {   // a already scaled by 2log2e
    return 1.0f - 2.0f * __builtin_amdgcn_rcpf(1.0f + __builtin_amdgcn_exp2f(a));
}

// In-loop barrier: LDS-visibility only. __syncthreads() forces the compiler to
// emit s_waitcnt vmcnt(0) before s_barrier, draining the prefetch global loads
// at full L3/HBM latency once per 4-step group. h-exchange needs ONLY
// lgkmcnt(0) (ds_write completion); vmem ordering is carried by the register
// dependency load->reg->ds_write. Pattern per guide §5 8-phase template.
#define BAR() do { \
    asm volatile("s_waitcnt lgkmcnt(0)" ::: "memory"); \
    __builtin_amdgcn_s_barrier(); \
} while (0)

// launch_bounds 2nd arg empirically == achieved blocks/CU for 256-thread
// blocks ((,4)->46% occ but VGPR crushed to 64 w/ 909MB spill; (,2)->VGPR 80,
// no spill). With 512 blocks, 2/CU is full coverage in one round.
__global__ __launch_bounds__(NTHREADS, 2)
void lstm_fused(const float* __restrict__ x,    const float* __restrict__ W_ih,
                const float* __restrict__ W_hh, const float* __restrict__ b_ih,
                const float* __restrict__ b_hh, const float* __restrict__ fc_W,
                const float* __restrict__ fc_b, float* __restrict__ out)
{
    __shared__ __align__(16) short Abuf[1024];

    const int tid  = threadIdx.x;
    const int w    = tid >> 6;        // wave 0..3 = hidden-col tile [16w,16w+16)
    const int lane = tid & 63;
    const int quad = lane >> 4;       // batch row this lane activates
    const int col  = lane & 15;
    const int b0   = blockIdx.x * ROWS;

    // zero h slots only (x slots are fully staged before first read)
    Abuf[HS0 + tid] = 0;
    Abuf[HS1 + tid] = 0;

    // ---- weight fragments (B layout: n = lane&15, k = quad*8+j), pre-scaled ----
    // kc 0,1: x-part (k 0..63 of W_ih); kc 2,3: h-part (W_hh). k=64 -> acc_x fold.
    bf16x8 wfrag[4][4];
    float  wl[4];
    f32x4  bias4[4];
    #pragma unroll
    for (int gt = 0; gt < 4; ++gt) {
        const float sc = (gt == 2) ? SGSCL : NLOG2E;
        const int n = gt * 64 + w * 16 + col;
        #pragma unroll
        for (int kc = 0; kc < 2; ++kc) {
            bf16x8 f;
            #pragma unroll
            for (int j = 0; j < 8; ++j)
                f[j] = f2bf(W_ih[n * INSZ + kc * 32 + quad * 8 + j] * sc);
            wfrag[gt][kc] = f;
        }
        #pragma unroll
        for (int kc = 2; kc < 4; ++kc) {
            bf16x8 f;
            #pragma unroll
            for (int j = 0; j < 8; ++j)
                f[j] = f2bf(W_hh[n * HID + (kc - 2) * 32 + quad * 8 + j] * sc);
            wfrag[gt][kc] = f;
        }
        wl[gt] = W_ih[n * INSZ + 64] * sc;
        const float bv = (b_ih[n] + b_hh[n]) * sc;
        bias4[gt] = (f32x4){bv, bv, bv, bv};
    }

    // A-frag replication: M-row m supplies data row m>>2. Lane (quad q) then
    // holds C rows 4q..4q+3 which ALL map to data row q -> gate = acc[gt][0],
    // no sel4 cndmasks on the serial chain. With ROWS=4, quad==batch row:
    // zero duplication in activation (64 lanes = 4 rows x 16 hidden).
    const int rbase = quad * 32 + (col >> 2) * 8;              // frag read
    const int hwoff = (2 * w + (col >> 3)) * 32 + quad * 8 + (col & 7);  // h write
    const int xwoff = (lane >> 3) * 32 + w * 8 + (lane & 7);   // x stage write

    // staging thread (w,lane) owns x[b0+w][.][lane]; fixup lane reads x[b0+quad][.][64]
    const float* xsp = x + (size_t)(b0 + w)    * T_STEPS * INSZ + lane;
    const float* xep = x + (size_t)(b0 + quad) * T_STEPS * INSZ + 64;

    // stage x_0 -> XS0, x_1 -> XS1; init 4-step register pipelines
    Abuf[XS0 + xwoff] = f2bf(xsp[0]);
    Abuf[XS1 + xwoff] = f2bf(xsp[INSZ]);
    float stg[4], fix[4];                 // stg: x_{t+2..t+5}; fix: x_{t+1..t+4}[64]
    const float fix0 = xep[0];
    #pragma unroll
    for (int i = 0; i < 4; ++i) {
        stg[i] = xsp[(2 + i) * INSZ];
        fix[i] = xep[(1 + i) * INSZ];
    }
    float c = 0.0f;
    f32x4 acc_x[4];
    __syncthreads();   // prologue: full sync (drains prologue loads, once)

    // acc_x(x_0) = bias + x_0 . W_ih, with the k=64 fixup folded in off-path
    {
        const bf16x8 n0 = *(const bf16x8*)&Abuf[XS0 + rbase];
        const bf16x8 n1 = *(const bf16x8*)&Abuf[XS0 + rbase + 128];
        #pragma unroll
        for (int gt = 0; gt < 4; ++gt) {
            f32x4 a = __builtin_amdgcn_mfma_f32_16x16x32_bf16(n0, wfrag[gt][0], bias4[gt], 0, 0, 0);
            acc_x[gt] = __builtin_amdgcn_mfma_f32_16x16x32_bf16(n1, wfrag[gt][1], a, 0, 0, 0);
            acc_x[gt][0] = __builtin_fmaf(wl[gt], fix0, acc_x[gt][0]);
        }
    }
    __syncthreads();    // x_0 frag reads done before body 0 overwrites XS0

    // one LSTM step. Critical path: ds_read h -> 8 MFMA -> activation -> h write.
    // acc_x for t+1 (8 MFMA + fixup fold) runs in the shadow of the activation.
    auto STEP = [&](int XR, int XW, int HR, int HW, float xfixn, float xstage) {
        const bf16x8 a2 = *(const bf16x8*)&Abuf[HR + rbase];        // h lo
        const bf16x8 a3 = *(const bf16x8*)&Abuf[HR + rbase + 128];  // h hi
        const bf16x8 n0 = *(const bf16x8*)&Abuf[XR + rbase];        // x_{t+1} lo
        const bf16x8 n1 = *(const bf16x8*)&Abuf[XR + rbase + 128];  // x_{t+1} hi
        f32x4 acc[4];
        #pragma unroll
        for (int gt = 0; gt < 4; ++gt) {
            f32x4 a = __builtin_amdgcn_mfma_f32_16x16x32_bf16(a2, wfrag[gt][2], acc_x[gt], 0, 0, 0);
            acc[gt]  = __builtin_amdgcn_mfma_f32_16x16x32_bf16(a3, wfrag[gt][3], a, 0, 0, 0);
        }
        const float gi = sigm2(acc[0][0]);
        const float gf = sigm2(acc[1][0]);
        const float gg = tanh2(acc[2][0]);
        const float go = sigm2(acc[3][0]);
        c = gf * c + gi * gg;
        const float h = go * tanh2(SGSCL * c);
        Abuf[HW + hwoff] = f2bf(h);          // h_t
        Abuf[XW + xwoff] = f2bf(xstage);     // x_{t+2}
        #pragma unroll
        for (int gt = 0; gt < 4; ++gt) {     // acc_x for step t+1 (off critical path)
            f32x4 a = __builtin_amdgcn_mfma_f32_16x16x32_bf16(n0, wfrag[gt][0], bias4[gt], 0, 0, 0);
            acc_x[gt] = __builtin_amdgcn_mfma_f32_16x16x32_bf16(n1, wfrag[gt][1], a, 0, 0, 0);
            acc_x[gt][0] = __builtin_fmaf(wl[gt], xfixn, acc_x[gt][0]);
        }
        BAR();   // lgkmcnt-only barrier: prefetch vmem stays in flight
    };

    for (int t = 0; t < T_STEPS; t += 4) {
        // global loads for the NEXT 4-step group; with BAR() they are never
        // drained at a barrier — latency hidden across the whole group.
        float ns[4], nf[4];
        #pragma unroll
        for (int i = 0; i < 4; ++i) {
            const int ts = t + 6 + i;  // stage x_{t+6+i} (clamped tail: unused)
            const int tf = t + 5 + i;  // fixup x_{t+5+i}[64]
            ns[i] = xsp[(ts < 255 ? ts : 255) * INSZ];
            nf[i] = xep[(tf < 255 ? tf : 255) * INSZ];
        }
        STEP(XS1, XS0, HS1, HS0, fix[0], stg[0]);   // t   : h in HS1, x_{t+1} in XS1
        STEP(XS0, XS1, HS0, HS1, fix[1], stg[1]);   // t+1
        STEP(XS1, XS0, HS1, HS0, fix[2], stg[2]);   // t+2
        STEP(XS0, XS1, HS0, HS1, fix[3], stg[3]);   // t+3
        #pragma unroll
        for (int i = 0; i < 4; ++i) { stg[i] = ns[i]; fix[i] = nf[i]; }
    }

    // ---- FC(64->7) + sigmoid; h_255 lives in HS1 (frag-major) ----
    // last STEP ended with BAR(): all h writes visible.
    if (tid < ROWS * OUTSZ) {
        const int m = tid & 3;
        const int o = tid >> 2;
        float s = fc_b[o];
        #pragma unroll
        for (int k = 0; k < HID; ++k)
            s += bf2f(Abuf[HS1 + (k >> 3) * 32 + m * 8 + (k & 7)]) * fc_W[o * HID + k];
        out[(size_t)(b0 + m) * OUTSZ + o] =
            __builtin_amdgcn_rcpf(1.0f + __builtin_amdgcn_exp2f(NLOG2E * s));
    }
}

extern "C" void kernel_launch(void* const* d_in, const int* in_sizes, int n_in,
                              void* d_out, int out_size, void* d_ws, size_t ws_size,
                              hipStream_t stream) {
    const float* x    = (const float*)d_in[0];
    const float* W_ih = (const float*)d_in[1];
    const float* W_hh = (const float*)d_in[2];
    const float* b_ih = (const float*)d_in[3];
    const float* b_hh = (const float*)d_in[4];
    const float* fc_W = (const float*)d_in[5];
    const float* fc_b = (const float*)d_in[6];
    float* out = (float*)d_out;

    dim3 grid(BATCH / ROWS);    // 512 blocks -> 2 per CU
    dim3 block(NTHREADS);       // 4 waves
    hipLaunchKernelGGL(lstm_fused, grid, block, 0, stream,
                       x, W_ih, W_hh, b_ih, b_hh, fc_W, fc_b, out);
}

// Round 5
// 263.150 us; speedup vs baseline: 5.0455x; 1.0108x over previous
//
#include <hip/hip_runtime.h>
#include <hip/hip_bf16.h>

#define T_STEPS 256
#define BATCH   2048
#define INSZ    65
#define HID     64
#define ROWS    4        // batch rows per block -> 512 blocks = 2 blocks/CU
#define OUTSZ   7
#define NTHREADS 256

// LDS slot bases (shorts). Frag-major layout inside each 256-short slot:
// element (row, k) at (k>>3)*32 + row*8 + (k&7).  b128 frag reads: <=2-way/bank.
#define XS0 0
#define XS1 256
#define HS0 512
#define HS1 768

typedef __attribute__((ext_vector_type(8))) short bf16x8;  // 8 bf16 = 4 VGPRs
typedef __attribute__((ext_vector_type(4))) float f32x4;

// f32->bf16 RNE via HIP intrinsic (round-2 post-mortem: no inline-asm cvt).
__device__ __forceinline__ short f2bf(float f) {
    __hip_bfloat16 b = __float2bfloat16(f);
    return (short)__builtin_bit_cast(unsigned short, b);
}
__device__ __forceinline__ float bf2f(short s) {
    union { unsigned u; float f; } v;
    v.u = ((unsigned)(unsigned short)s) << 16;
    return v.f;
}

// Gate pre-activations arrive PRE-SCALED (folded into weights/bias):
//   i,f,o scaled by -log2(e)  -> sigmoid(x) = rcp(1 + exp2(x'))
//   g     scaled by +2log2(e) -> tanh(x)    = 1 - 2*rcp(1 + exp2(x'))
// Cell state is carried PRE-SCALED: c' = 2log2(e)*c, maintained by pre-scaling
// the g-gate output (gg' = SGSCL*tanh = fma(r,-2*SGSCL,SGSCL), same op count).
// Final tanh(c) = 1 - 2*rcp(1+exp2(c')) -- no mul on the c->h critical chain.
#define NLOG2E -1.4426950408889634f
#define SGSCL   2.8853900817779268f

__device__ __forceinline__ float sigm2(float a) {
    return __builtin_amdgcn_rcpf(1.0f + __builtin_amdgcn_exp2f(a));
}

// In-loop barrier: LDS-visibility only (lgkmcnt). __syncthreads() would drain
// vmcnt(0) too, stalling on the prefetch global loads (round-4 win: 191->128us).
#define BAR() do { \
    asm volatile("s_waitcnt lgkmcnt(0)" ::: "memory"); \
    __builtin_amdgcn_s_barrier(); \
} while (0)

// launch_bounds(,2): VGPR cap 256 -> 80 alloc, no spill (rounds 3/4 proven).
// (,4) caps arch VGPRs at 64 -> 909MB scratch spill (round-1 disaster).
// TLP ceiling: grid=512 on 256 CUs = 2 blocks/CU exactly, by design.
__global__ __launch_bounds__(NTHREADS, 2)
void lstm_fused(const float* __restrict__ x,    const float* __restrict__ W_ih,
                const float* __restrict__ W_hh, const float* __restrict__ b_ih,
                const float* __restrict__ b_hh, const float* __restrict__ fc_W,
                const float* __restrict__ fc_b, float* __restrict__ out)
{
    __shared__ __align__(16) short Abuf[1024];

    const int tid  = threadIdx.x;
    const int w    = tid >> 6;        // wave 0..3 = hidden-col tile [16w,16w+16)
    const int lane = tid & 63;
    const int quad = lane >> 4;       // batch row this lane activates
    const int col  = lane & 15;
    const int b0   = blockIdx.x * ROWS;

    // zero h slots only (x slots are fully staged before first read)
    Abuf[HS0 + tid] = 0;
    Abuf[HS1 + tid] = 0;

    // ---- weight fragments (B layout: n = lane&15, k = quad*8+j), pre-scaled ----
    // kc 0,1: x-part (k 0..63 of W_ih); kc 2,3: h-part (W_hh). k=64 -> acc_x fold.
    bf16x8 wfrag[4][4];
    float  wl[4];
    f32x4  bias4[4];
    #pragma unroll
    for (int gt = 0; gt < 4; ++gt) {
        const float sc = (gt == 2) ? SGSCL : NLOG2E;
        const int n = gt * 64 + w * 16 + col;
        #pragma unroll
        for (int kc = 0; kc < 2; ++kc) {
            bf16x8 f;
            #pragma unroll
            for (int j = 0; j < 8; ++j)
                f[j] = f2bf(W_ih[n * INSZ + kc * 32 + quad * 8 + j] * sc);
            wfrag[gt][kc] = f;
        }
        #pragma unroll
        for (int kc = 2; kc < 4; ++kc) {
            bf16x8 f;
            #pragma unroll
            for (int j = 0; j < 8; ++j)
                f[j] = f2bf(W_hh[n * HID + (kc - 2) * 32 + quad * 8 + j] * sc);
            wfrag[gt][kc] = f;
        }
        wl[gt] = W_ih[n * INSZ + 64] * sc;
        const float bv = (b_ih[n] + b_hh[n]) * sc;
        bias4[gt] = (f32x4){bv, bv, bv, bv};
    }

    // A-frag replication: M-row m supplies data row m>>2. Lane (quad q) then
    // holds C rows 4q..4q+3 which ALL map to data row q -> gate = acc[gt][0],
    // no sel4 cndmasks on the serial chain. With ROWS=4, quad==batch row.
    const int rbase = quad * 32 + (col >> 2) * 8;              // frag read
    const int hwoff = (2 * w + (col >> 3)) * 32 + quad * 8 + (col & 7);  // h write
    const int xwoff = (lane >> 3) * 32 + w * 8 + (lane & 7);   // x stage write

    // staging thread (w,lane) owns x[b0+w][.][lane]; fixup lane reads x[b0+quad][.][64]
    const float* xsp = x + (size_t)(b0 + w)    * T_STEPS * INSZ + lane;
    const float* xep = x + (size_t)(b0 + quad) * T_STEPS * INSZ + 64;

    // stage x_0 -> XS0, x_1 -> XS1; init 4-step register pipelines
    Abuf[XS0 + xwoff] = f2bf(xsp[0]);
    Abuf[XS1 + xwoff] = f2bf(xsp[INSZ]);
    float stg[4], fix[4];                 // stg: x_{t+2..t+5}; fix: x_{t+1..t+4}[64]
    const float fix0 = xep[0];
    #pragma unroll
    for (int i = 0; i < 4; ++i) {
        stg[i] = xsp[(2 + i) * INSZ];
        fix[i] = xep[(1 + i) * INSZ];
    }
    float c = 0.0f;   // carried pre-scaled: c' = SGSCL * c_true
    f32x4 acc_x[4];
    __syncthreads();   // prologue: full sync (drains prologue loads, once)

    // acc_x(x_0) = bias + x_0 . W_ih, with the k=64 fixup folded in off-path
    {
        const bf16x8 n0 = *(const bf16x8*)&Abuf[XS0 + rbase];
        const bf16x8 n1 = *(const bf16x8*)&Abuf[XS0 + rbase + 128];
        #pragma unroll
        for (int gt = 0; gt < 4; ++gt) {
            f32x4 a = __builtin_amdgcn_mfma_f32_16x16x32_bf16(n0, wfrag[gt][0], bias4[gt], 0, 0, 0);
            acc_x[gt] = __builtin_amdgcn_mfma_f32_16x16x32_bf16(n1, wfrag[gt][1], a, 0, 0, 0);
            acc_x[gt][0] = __builtin_fmaf(wl[gt], fix0, acc_x[gt][0]);
        }
    }
    __syncthreads();    // x_0 frag reads done before body 0 overwrites XS0

    // one LSTM step. Critical path: ds_read h -> 8 MFMA -> activation -> h write.
    // setprio(1) covers it; setprio(0) for the off-path acc_x MFMAs + barrier
    // wait. The co-resident block's waves run anti-phased on the same SIMDs —
    // priority steers issue to whichever wave is in its serial chain (T5).
    auto STEP = [&](int XR, int XW, int HR, int HW, float xfixn, float xstage) {
        __builtin_amdgcn_s_setprio(1);
        const bf16x8 a2 = *(const bf16x8*)&Abuf[HR + rbase];        // h lo
        const bf16x8 a3 = *(const bf16x8*)&Abuf[HR + rbase + 128];  // h hi
        const bf16x8 n0 = *(const bf16x8*)&Abuf[XR + rbase];        // x_{t+1} lo
        const bf16x8 n1 = *(const bf16x8*)&Abuf[XR + rbase + 128];  // x_{t+1} hi
        f32x4 acc[4];
        #pragma unroll
        for (int gt = 0; gt < 4; ++gt) {
            f32x4 a = __builtin_amdgcn_mfma_f32_16x16x32_bf16(a2, wfrag[gt][2], acc_x[gt], 0, 0, 0);
            acc[gt]  = __builtin_amdgcn_mfma_f32_16x16x32_bf16(a3, wfrag[gt][3], a, 0, 0, 0);
        }
        const float gi = sigm2(acc[0][0]);
        const float gf = sigm2(acc[1][0]);
        // g-gate pre-scaled by SGSCL: gg = SGSCL*tanh(g) = SGSCL - 2*SGSCL*r
        const float rg = __builtin_amdgcn_rcpf(1.0f + __builtin_amdgcn_exp2f(acc[2][0]));
        const float gg = __builtin_fmaf(rg, -2.0f * SGSCL, SGSCL);
        const float go = sigm2(acc[3][0]);
        c = __builtin_fmaf(gf, c, gi * gg);          // c' = SGSCL*c_true
        const float rc = __builtin_amdgcn_rcpf(1.0f + __builtin_amdgcn_exp2f(c));
        const float th = __builtin_fmaf(rc, -2.0f, 1.0f);   // tanh(c_true)
        const float h  = go * th;
        Abuf[HW + hwoff] = f2bf(h);          // h_t
        Abuf[XW + xwoff] = f2bf(xstage);     // x_{t+2}
        __builtin_amdgcn_s_setprio(0);
        #pragma unroll
        for (int gt = 0; gt < 4; ++gt) {     // acc_x for step t+1 (off critical path)
            f32x4 a = __builtin_amdgcn_mfma_f32_16x16x32_bf16(n0, wfrag[gt][0], bias4[gt], 0, 0, 0);
            acc_x[gt] = __builtin_amdgcn_mfma_f32_16x16x32_bf16(n1, wfrag[gt][1], a, 0, 0, 0);
            acc_x[gt][0] = __builtin_fmaf(wl[gt], xfixn, acc_x[gt][0]);
        }
        BAR();   // lgkmcnt-only barrier: prefetch vmem stays in flight
    };

    for (int t = 0; t < T_STEPS; t += 4) {
        // global loads for the NEXT 4-step group; with BAR() they are never
        // drained at a barrier — latency hidden across the whole group.
        float ns[4], nf[4];
        #pragma unroll
        for (int i = 0; i < 4; ++i) {
            const int ts = t + 6 + i;  // stage x_{t+6+i} (clamped tail: unused)
            const int tf = t + 5 + i;  // fixup x_{t+5+i}[64]
            ns[i] = xsp[(ts < 255 ? ts : 255) * INSZ];
            nf[i] = xep[(tf < 255 ? tf : 255) * INSZ];
        }
        STEP(XS1, XS0, HS1, HS0, fix[0], stg[0]);   // t   : h in HS1, x_{t+1} in XS1
        STEP(XS0, XS1, HS0, HS1, fix[1], stg[1]);   // t+1
        STEP(XS1, XS0, HS1, HS0, fix[2], stg[2]);   // t+2
        STEP(XS0, XS1, HS0, HS1, fix[3], stg[3]);   // t+3
        #pragma unroll
        for (int i = 0; i < 4; ++i) { stg[i] = ns[i]; fix[i] = nf[i]; }
    }

    // ---- FC(64->7) + sigmoid; h_255 lives in HS1 (frag-major) ----
    // last STEP ended with BAR(): all h writes visible.
    if (tid < ROWS * OUTSZ) {
        const int m = tid & 3;
        const int o = tid >> 2;
        float s = fc_b[o];
        #pragma unroll
        for (int k = 0; k < HID; ++k)
            s += bf2f(Abuf[HS1 + (k >> 3) * 32 + m * 8 + (k & 7)]) * fc_W[o * HID + k];
        out[(size_t)(b0 + m) * OUTSZ + o] =
            __builtin_amdgcn_rcpf(1.0f + __builtin_amdgcn_exp2f(NLOG2E * s));
    }
}

extern "C" void kernel_launch(void* const* d_in, const int* in_sizes, int n_in,
                              void* d_out, int out_size, void* d_ws, size_t ws_size,
                              hipStream_t stream) {
    const float* x    = (const float*)d_in[0];
    const float* W_ih = (const float*)d_in[1];
    const float* W_hh = (const float*)d_in[2];
    const float* b_ih = (const float*)d_in[3];
    const float* b_hh = (const float*)d_in[4];
    const float* fc_W = (const float*)d_in[5];
    const float* fc_b = (const float*)d_in[6];
    float* out = (float*)d_out;

    dim3 grid(BATCH / ROWS);    // 512 blocks -> 2 per CU
    dim3 block(NTHREADS);       // 4 waves
    hipLaunchKernelGGL(lstm_fused, grid, block, 0, stream,
                       x, W_ih, W_hh, b_ih, b_hh, fc_W, fc_b, out);
}

// Round 7
// 242.599 us; speedup vs baseline: 5.4729x; 1.0847x over previous
//
#include <hip/hip_runtime.h>
#include <hip/hip_bf16.h>
#include <type_traits>

#define T_STEPS 256
#define BATCH   2048
#define INSZ    65
#define HID     64
#define ROWS    4        // batch rows per block -> 512 blocks = 2 blocks/CU
#define OUTSZ   7
#define NTHREADS 256

// LDS (shorts):
//  XB [0,1024): x A-tile for one 4-step group, M=16 (m = 4*row + tstep_local),
//               K=64 frag-major: element(m,k) at (k>>3)*128 + m*8 + (k&7)
//  HS0/HS1 [1024,1536): h slots (256 shorts each),
//               element(row,k) at (k>>3)*32 + row*8 + (k&7)
#define XB   0
#define HS0  1024
#define HS1  1280

typedef __attribute__((ext_vector_type(8))) short bf16x8;  // 8 bf16 = 4 VGPRs
typedef __attribute__((ext_vector_type(4))) short short4v; // 4 bf16 = 2 VGPRs
typedef __attribute__((ext_vector_type(4))) float f32x4;

// f32->bf16 RNE via HIP intrinsic (round-2 post-mortem: no inline-asm cvt).
__device__ __forceinline__ short f2bf(float f) {
    __hip_bfloat16 b = __float2bfloat16(f);
    return (short)__builtin_bit_cast(unsigned short, b);
}
__device__ __forceinline__ float bf2f(short s) {
    union { unsigned u; float f; } v;
    v.u = ((unsigned)(unsigned short)s) << 16;
    return v.f;
}

// Gate pre-activations PRE-SCALED (folded into weights/bias):
//   i,f,o scaled by -log2(e)  -> sigmoid(x) = rcp(1 + exp2(x'))
//   g     scaled by +2log2(e); cell state carried pre-scaled c' = 2log2(e)*c
#define NLOG2E -1.4426950408889634f
#define SGSCL   2.8853900817779268f

__device__ __forceinline__ float sigm2(float a) {
    return __builtin_amdgcn_rcpf(1.0f + __builtin_amdgcn_exp2f(a));
}

// LDS-visibility-only barrier (round-4 win: no vmcnt drain; prefetch global
// loads stay in flight across barriers).
#define BAR() do { \
    asm volatile("s_waitcnt lgkmcnt(0)" ::: "memory"); \
    __builtin_amdgcn_s_barrier(); \
} while (0)

#define IC(n) std::integral_constant<int, n>{}

// launch_bounds(,2): VGPR cap 256, no spill (rounds 3-5 proven).
// (,4) caps arch VGPRs at 64 -> 909MB scratch spill (round-1 disaster).
__global__ __launch_bounds__(NTHREADS, 2)
void lstm_fused(const float* __restrict__ x,    const float* __restrict__ W_ih,
                const float* __restrict__ W_hh, const float* __restrict__ b_ih,
                const float* __restrict__ b_hh, const float* __restrict__ fc_W,
                const float* __restrict__ fc_b, float* __restrict__ out)
{
    __shared__ __align__(16) short Abuf[1536];

    const int tid  = threadIdx.x;
    const int w    = tid >> 6;        // wave 0..3 = hidden-col tile [16w,16w+16)
    const int lane = tid & 63;
    const int quad = lane >> 4;       // batch row this lane activates / tl for staging
    const int col  = lane & 15;
    const int b0   = blockIdx.x * ROWS;

    // zero h slots (x buffer fully staged before first read)
    Abuf[HS0 + tid] = 0;   // covers HS0 ...
    Abuf[HS1 + tid] = 0;   // ... and HS1

    // ---- weight fragments (B layout: n = lane&15, k = quad*8+j), pre-scaled ----
    // kc 0,1: x-part (k 0..63 of W_ih); kc 2,3: h-part (W_hh). k=64 -> acc_bx fold.
    bf16x8 wfrag[4][4];
    float  wl[4];
    f32x4  bias4[4];
    #pragma unroll
    for (int gt = 0; gt < 4; ++gt) {
        const float sc = (gt == 2) ? SGSCL : NLOG2E;
        const int n = gt * 64 + w * 16 + col;
        #pragma unroll
        for (int kc = 0; kc < 2; ++kc) {
            bf16x8 f;
            #pragma unroll
            for (int j = 0; j < 8; ++j)
                f[j] = f2bf(W_ih[n * INSZ + kc * 32 + quad * 8 + j] * sc);
            wfrag[gt][kc] = f;
        }
        #pragma unroll
        for (int kc = 2; kc < 4; ++kc) {
            bf16x8 f;
            #pragma unroll
            for (int j = 0; j < 8; ++j)
                f[j] = f2bf(W_hh[n * HID + (kc - 2) * 32 + quad * 8 + j] * sc);
            wfrag[gt][kc] = f;
        }
        wl[gt] = W_ih[n * INSZ + 64] * sc;
        const float bv = (b_ih[n] + b_hh[n]) * sc;
        bias4[gt] = (f32x4){bv, bv, bv, bv};
    }

    // h A-frag read: A row m holds h[row m>>2] (replication) -> gate at any reg.
    const int rbase = quad * 32 + (col >> 2) * 8;
    // batched-x A-frag read: A row m = col holds x[row m>>2][t + (m&3)][k]
    const int rbx   = quad * 128 + col * 8;
    const int hwoff = (2 * w + (col >> 3)) * 32 + quad * 8 + (col & 7);  // h write
    // x stage write: thread (w,lane) owns (row w, tl=quad, feats col*4..col*4+3)
    //   m = 4*w + quad; k = col*4 -> addr = (col>>1)*128 + m*8 + (col&1)*4
    const int xswoff = (col >> 1) * 128 + (4 * w + quad) * 8 + (col & 1) * 4;

    const float* xr  = x + (size_t)(b0 + w)    * T_STEPS * INSZ;       // staging row
    const float* xep = x + (size_t)(b0 + quad) * T_STEPS * INSZ + 64;  // k=64 fixup

    // ---- prologue: stage group 0 (ts = quad), preload ldA (ts = 4+quad) ----
    {
        short4v pk0;
        #pragma unroll
        for (int j = 0; j < 4; ++j)
            pk0[j] = f2bf(xr[quad * INSZ + col * 4 + j]);
        *(short4v*)&Abuf[XB + xswoff] = pk0;
    }
    float ldA[4];
    #pragma unroll
    for (int j = 0; j < 4; ++j) ldA[j] = xr[(4 + quad) * INSZ + col * 4 + j];
    float fx[4];
    #pragma unroll
    for (int s = 0; s < 4; ++s) fx[s] = xep[s * INSZ];
    float c = 0.0f;   // carried pre-scaled: c' = SGSCL * c_true
    f32x4 acc_bx[4];
    __syncthreads();

    // batched x-MFMA for group 0: acc_bx[gt] reg s = bias + xg[row quad][t=s][col]
    {
        const bf16x8 xb0 = *(const bf16x8*)&Abuf[XB + rbx];
        const bf16x8 xb1 = *(const bf16x8*)&Abuf[XB + rbx + 512];
        #pragma unroll
        for (int gt = 0; gt < 4; ++gt) {
            f32x4 a = __builtin_amdgcn_mfma_f32_16x16x32_bf16(xb0, wfrag[gt][0], bias4[gt], 0, 0, 0);
            a = __builtin_amdgcn_mfma_f32_16x16x32_bf16(xb1, wfrag[gt][1], a, 0, 0, 0);
            #pragma unroll
            for (int i = 0; i < 4; ++i)
                a[i] = __builtin_fmaf(wl[gt], fx[i], a[i]);
            acc_bx[gt] = a;
        }
    }
    // no barrier needed: XB next written in s1 (post-BAR(s0)); s0 reads zeroed HS1.

    // One LSTM step. Critical path: ds_read h -> 8 MFMA -> activation -> h write.
    // Gate value for step S is g[gt][S]: the batched x-MFMA put xg[row q][t+S]
    // in C-reg S, and the h-part adds the same h-contribution to all 4 regs.
    // shadow(): off-critical-path work issued before the barrier.
    // (round-5 A/B: s_setprio here was neutral-to-negative -> not used)
    auto lstm_step = [&](auto Sc, int HR, int HW, auto&& shadow) {
        constexpr int S = decltype(Sc)::value;
        const bf16x8 a2 = *(const bf16x8*)&Abuf[HR + rbase];        // h lo
        const bf16x8 a3 = *(const bf16x8*)&Abuf[HR + rbase + 128];  // h hi
        f32x4 g0 = __builtin_amdgcn_mfma_f32_16x16x32_bf16(a2, wfrag[0][2], acc_bx[0], 0, 0, 0);
        g0 = __builtin_amdgcn_mfma_f32_16x16x32_bf16(a3, wfrag[0][3], g0, 0, 0, 0);
        f32x4 g1 = __builtin_amdgcn_mfma_f32_16x16x32_bf16(a2, wfrag[1][2], acc_bx[1], 0, 0, 0);
        g1 = __builtin_amdgcn_mfma_f32_16x16x32_bf16(a3, wfrag[1][3], g1, 0, 0, 0);
        f32x4 g2 = __builtin_amdgcn_mfma_f32_16x16x32_bf16(a2, wfrag[2][2], acc_bx[2], 0, 0, 0);
        g2 = __builtin_amdgcn_mfma_f32_16x16x32_bf16(a3, wfrag[2][3], g2, 0, 0, 0);
        f32x4 g3 = __builtin_amdgcn_mfma_f32_16x16x32_bf16(a2, wfrag[3][2], acc_bx[3], 0, 0, 0);
        g3 = __builtin_amdgcn_mfma_f32_16x16x32_bf16(a3, wfrag[3][3], g3, 0, 0, 0);
        const float gi = sigm2(g0[S]);
        const float gf = sigm2(g1[S]);
        // g-gate pre-scaled by SGSCL: gg = SGSCL*tanh(g) = SGSCL - 2*SGSCL*r
        const float rg = __builtin_amdgcn_rcpf(1.0f + __builtin_amdgcn_exp2f(g2[S]));
        const float gg = __builtin_fmaf(rg, -2.0f * SGSCL, SGSCL);
        const float go = sigm2(g3[S]);
        c = __builtin_fmaf(gf, c, gi * gg);          // c' = SGSCL*c_true
        const float rc = __builtin_amdgcn_rcpf(1.0f + __builtin_amdgcn_exp2f(c));
        const float h  = go * __builtin_fmaf(rc, -2.0f, 1.0f);
        Abuf[HW + hwoff] = f2bf(h);                  // h_t
        shadow();
        BAR();   // lgkmcnt-only: prefetch vmem stays in flight
    };

    for (int t = 0; t < T_STEPS; t += 4) {
        // group-top global loads (never drained at a barrier):
        //   ldB: x feats for group t+8 (consumed next group)
        //   nf : k=64 fixup values for group t+4 (consumed in s3 shadow)
        int tsb = t + 8 + quad; tsb = tsb > 255 ? 255 : tsb;
        float ldB[4], nf[4];
        #pragma unroll
        for (int j = 0; j < 4; ++j) ldB[j] = xr[tsb * INSZ + col * 4 + j];
        #pragma unroll
        for (int s = 0; s < 4; ++s) {
            int tf = t + 4 + s; tf = tf > 255 ? 255 : tf;
            nf[s] = xep[tf * INSZ];
        }
        short4v pk;
        // s0: convert ldA (group t+4 feats) to bf16 in the activation shadow
        lstm_step(IC(0), HS1, HS0, [&] {
            #pragma unroll
            for (int j = 0; j < 4; ++j) pk[j] = f2bf(ldA[j]);
        });
        // s1: stage write (post-BAR(s0): prior XB readers done; its own reader
        // is s3, one barrier later)
        lstm_step(IC(1), HS0, HS1, [&] {
            *(short4v*)&Abuf[XB + xswoff] = pk;
        });
        lstm_step(IC(2), HS1, HS0, [&] {});
        // s3: batched x-MFMA for group t+4 (8 MFMA + fixup fma, off-path);
        // old acc_bx consumed by this step's h-MFMA above, safe to overwrite.
        lstm_step(IC(3), HS0, HS1, [&] {
            const bf16x8 xb0 = *(const bf16x8*)&Abuf[XB + rbx];
            const bf16x8 xb1 = *(const bf16x8*)&Abuf[XB + rbx + 512];
            #pragma unroll
            for (int gt = 0; gt < 4; ++gt) {
                f32x4 a = __builtin_amdgcn_mfma_f32_16x16x32_bf16(xb0, wfrag[gt][0], bias4[gt], 0, 0, 0);
                a = __builtin_amdgcn_mfma_f32_16x16x32_bf16(xb1, wfrag[gt][1], a, 0, 0, 0);
                #pragma unroll
                for (int i = 0; i < 4; ++i)
                    a[i] = __builtin_fmaf(wl[gt], nf[i], a[i]);
                acc_bx[gt] = a;
            }
            #pragma unroll
            for (int j = 0; j < 4; ++j) ldA[j] = ldB[j];
        });
    }

    // ---- FC(64->7) + sigmoid; h_255 lives in HS1 (frag-major) ----
    // last step ended with BAR(): all h writes visible.
    if (tid < ROWS * OUTSZ) {
        const int m = tid & 3;
        const int o = tid >> 2;
        float s = fc_b[o];
        #pragma unroll
        for (int k = 0; k < HID; ++k)
            s += bf2f(Abuf[HS1 + (k >> 3) * 32 + m * 8 + (k & 7)]) * fc_W[o * HID + k];
        out[(size_t)(b0 + m) * OUTSZ + o] =
            __builtin_amdgcn_rcpf(1.0f + __builtin_amdgcn_exp2f(NLOG2E * s));
    }
}

extern "C" void kernel_launch(void* const* d_in, const int* in_sizes, int n_in,
                              void* d_out, int out_size, void* d_ws, size_t ws_size,
                              hipStream_t stream) {
    const float* x    = (const float*)d_in[0];
    const float* W_ih = (const float*)d_in[1];
    const float* W_hh = (const float*)d_in[2];
    const float* b_ih = (const float*)d_in[3];
    const float* b_hh = (const float*)d_in[4];
    const float* fc_W = (const float*)d_in[5];
    const float* fc_b = (const float*)d_in[6];
    float* out = (float*)d_out;

    dim3 grid(BATCH / ROWS);    // 512 blocks -> 2 per CU
    dim3 block(NTHREADS);       // 4 waves
    hipLaunchKernelGGL(lstm_fused, grid, block, 0, stream,
                       x, W_ih, W_hh, b_ih, b_hh, fc_W, fc_b, out);
}